// Round 7
// baseline (387.830 us; speedup 1.0000x reference)
//
#include <hip/hip_runtime.h>
#include <math.h>

#define TOKENS 16384
#define DMODEL 2048
#define NEXP   256
#define TOPK   8
#define BM     32
#define KC     256              // k-chunk (floats) staged in LDS per barrier
#define NCH    (DMODEL / KC)    // 8 chunks
#define NTIL   (DMODEL / 32)    // 64 flat k-tiles
#define RS     264              // LDS row stride in halfs (256 + 8 pad)

typedef _Float16 f16;
typedef _Float16 f16x8 __attribute__((ext_vector_type(8)));
typedef _Float16 f16x4 __attribute__((ext_vector_type(4)));
typedef float    f32x4 __attribute__((ext_vector_type(4)));

// barrier that drains ONLY lgkm (LDS); global prefetch stays in flight
#define BAR() asm volatile("s_waitcnt lgkmcnt(0)\ns_barrier" ::: "memory")

// f32x4 -> split-f16 (hi, lo*2048) -> LDS
static __device__ __forceinline__ void cvt_write(f16* AHp, f16* ALp, f32x4 v) {
    f16 h0 = (f16)v.x, h1 = (f16)v.y, h2 = (f16)v.z, h3 = (f16)v.w;
    f16x4 hv = {h0, h1, h2, h3};
    f16x4 lv = {(f16)((v.x - (float)h0) * 2048.0f),
                (f16)((v.y - (float)h1) * 2048.0f),
                (f16)((v.z - (float)h2) * 2048.0f),
                (f16)((v.w - (float)h3) * 2048.0f)};
    *(f16x4*)AHp = hv;
    *(f16x4*)ALp = lv;
}

// ---------------- prep: w (E x D f32) -> fp16 split planes, tile-major; zero counts/ctr ----------------
__global__ void k_prep(const float* __restrict__ w,
                       f16* __restrict__ wsH, f16* __restrict__ wsL,
                       float* __restrict__ counts, unsigned* __restrict__ ctr) {
    const int tid = threadIdx.x;
    if (blockIdx.x == 0) {
        counts[tid] = 0.0f;
        if (tid == 0 && ctr) *ctr = 0u;
    }
    const int g8 = (blockIdx.x * 256 + tid) * 8;
    const int ki = g8 & 31;
    const int e  = (g8 >> 5) & 255;
    const int t  = g8 >> 13;
    const float* src = w + (size_t)e * DMODEL + t * 32 + ki;
    f16x8 hv, lv;
#pragma unroll
    for (int i = 0; i < 8; i++) {
        float v = src[i] * 64.0f;
        f16 h = (f16)v;
        hv[i] = h;
        lv[i] = (f16)((v - (float)h) * 2048.0f);
    }
    *(f16x8*)(wsH + g8) = hv;
    *(f16x8*)(wsL + g8) = lv;
}

__global__ void k_zero(float* __restrict__ counts) {
    counts[threadIdx.x] = 0.0f;
}

// ---------------- main: 8-wave, depth-4 B pipeline, dbuf-A, split-fp16 MFMA + top-8 + stats ----------------
__global__ __launch_bounds__(512, 4) void k_main(
        const float* __restrict__ x,
        const f16*   __restrict__ wh,
        const f16*   __restrict__ wl,
        const float* __restrict__ bias,
        float* __restrict__ out,
        unsigned* __restrict__ ctr) {
    // double-buffered A (hi+lo per buf); logits overlays the same LDS after the GEMM
    __shared__ __align__(16) char raw[4 * BM * RS * sizeof(f16)];   // 67584 B >= 32768 (logits)
    __shared__ float hist[NEXP];
    __shared__ unsigned lastflag;

    f16* bufH0 = (f16*)raw;
    f16* bufL0 = bufH0 + BM * RS;
    f16* bufH1 = bufH0 + 2 * BM * RS;
    f16* bufL1 = bufH0 + 3 * BM * RS;
    float (*logits)[NEXP] = (float (*)[NEXP])raw;

    const int tid  = threadIdx.x;
    const int tok0 = blockIdx.x * BM;
    const int lane = tid & 63;
    const int wv   = tid >> 6;            // 0..7, owns experts wv*32..wv*32+31
    const int eb   = lane & 15;
    const int kq   = lane >> 4;           // 0..3

    if (tid < NEXP) hist[tid] = 0.0f;

    // ---- x staging: thread -> token (tid>>4), 4 x f32x4 at (tid&15)*4 + s*64 ----
    const int s_tok  = tid >> 4;          // 0..31
    const int s_lane = tid & 15;          // 0..15
    const float* xb = x + (size_t)(tok0 + s_tok) * DMODEL + s_lane * 4;
    const int wbase = s_tok * RS + s_lane * 4;      // halfs

    // ---- A fragment read offsets (halfs) ----
    const int ro0 = eb * RS + kq * 8;
    const int ro1 = (16 + eb) * RS + kq * 8;

    // ---- B fragment offsets within a k-tile (halfs): wave owns 2 n-frags ----
    const int bo0 = (wv * 32 + eb) * 32 + kq * 8;
    const int bo1 = (wv * 32 + 16 + eb) * 32 + kq * 8;

    f32x4 acc0[2][2], acc1[2][2];
#pragma unroll
    for (int m = 0; m < 2; m++)
#pragma unroll
        for (int n = 0; n < 2; n++) {
            acc0[m][n] = (f32x4){0.0f, 0.0f, 0.0f, 0.0f};
            acc1[m][n] = (f32x4){0.0f, 0.0f, 0.0f, 0.0f};
        }

    // ---- prologue: stage x chunk 0 into buf0; prime 4-deep B pipeline (tiles 0..3) ----
    {
        f32x4 v0 = *(const f32x4*)(xb);
        f32x4 v1 = *(const f32x4*)(xb + 64);
        f32x4 v2 = *(const f32x4*)(xb + 128);
        f32x4 v3 = *(const f32x4*)(xb + 192);
        cvt_write(bufH0 + wbase,       bufL0 + wbase,       v0);
        cvt_write(bufH0 + wbase + 64,  bufL0 + wbase + 64,  v1);
        cvt_write(bufH0 + wbase + 128, bufL0 + wbase + 128, v2);
        cvt_write(bufH0 + wbase + 192, bufL0 + wbase + 192, v3);
    }
    f16x8 pb[4][4];                       // [slot][bh0,bh1,bl0,bl1] — static-indexed only
#pragma unroll
    for (int s = 0; s < 4; ++s) {
        const f16* ph = wh + (size_t)s * (NEXP * 32);
        const f16* pl = wl + (size_t)s * (NEXP * 32);
        pb[s][0] = *(const f16x8*)(ph + bo0);
        pb[s][1] = *(const f16x8*)(ph + bo1);
        pb[s][2] = *(const f16x8*)(pl + bo0);
        pb[s][3] = *(const f16x8*)(pl + bo1);
    }
    BAR();

// one tile: ds_read A, 12 MFMA (per-acc chain order identical to prior passing kernel),
// then reissue this slot 4 tiles ahead (counted vmcnt keeps 12 B-loads in flight)
#define STEP(j) do {                                                                               \
    const int co = (j) * 32;                                                                       \
    f16x8 a0h = *(const f16x8*)(AHc + ro0 + co);                                                   \
    f16x8 a1h = *(const f16x8*)(AHc + ro1 + co);                                                   \
    f16x8 a0l = *(const f16x8*)(ALc + ro0 + co);                                                   \
    f16x8 a1l = *(const f16x8*)(ALc + ro1 + co);                                                   \
    __builtin_amdgcn_s_setprio(1);                                                                 \
    acc0[0][0] = __builtin_amdgcn_mfma_f32_16x16x32_f16(a0h, pb[(j)&3][0], acc0[0][0], 0, 0, 0);   \
    acc0[1][0] = __builtin_amdgcn_mfma_f32_16x16x32_f16(a1h, pb[(j)&3][0], acc0[1][0], 0, 0, 0);   \
    acc0[0][1] = __builtin_amdgcn_mfma_f32_16x16x32_f16(a0h, pb[(j)&3][1], acc0[0][1], 0, 0, 0);   \
    acc0[1][1] = __builtin_amdgcn_mfma_f32_16x16x32_f16(a1h, pb[(j)&3][1], acc0[1][1], 0, 0, 0);   \
    acc1[0][0] = __builtin_amdgcn_mfma_f32_16x16x32_f16(a0l, pb[(j)&3][0], acc1[0][0], 0, 0, 0);   \
    acc1[1][0] = __builtin_amdgcn_mfma_f32_16x16x32_f16(a1l, pb[(j)&3][0], acc1[1][0], 0, 0, 0);   \
    acc1[0][1] = __builtin_amdgcn_mfma_f32_16x16x32_f16(a0l, pb[(j)&3][1], acc1[0][1], 0, 0, 0);   \
    acc1[1][1] = __builtin_amdgcn_mfma_f32_16x16x32_f16(a1l, pb[(j)&3][1], acc1[1][1], 0, 0, 0);   \
    acc1[0][0] = __builtin_amdgcn_mfma_f32_16x16x32_f16(a0h, pb[(j)&3][2], acc1[0][0], 0, 0, 0);   \
    acc1[1][0] = __builtin_amdgcn_mfma_f32_16x16x32_f16(a1h, pb[(j)&3][2], acc1[1][0], 0, 0, 0);   \
    acc1[0][1] = __builtin_amdgcn_mfma_f32_16x16x32_f16(a0h, pb[(j)&3][3], acc1[0][1], 0, 0, 0);   \
    acc1[1][1] = __builtin_amdgcn_mfma_f32_16x16x32_f16(a1h, pb[(j)&3][3], acc1[1][1], 0, 0, 0);   \
    __builtin_amdgcn_s_setprio(0);                                                                 \
    if ((c < NCH - 1) || ((j) < 4)) {                                                              \
        const int t4 = c * 8 + (j) + 4;                                                            \
        const f16* ph = wh + (size_t)t4 * (NEXP * 32);                                             \
        const f16* pl = wl + (size_t)t4 * (NEXP * 32);                                             \
        pb[(j)&3][0] = *(const f16x8*)(ph + bo0);                                                  \
        pb[(j)&3][1] = *(const f16x8*)(ph + bo1);                                                  \
        pb[(j)&3][2] = *(const f16x8*)(pl + bo0);                                                  \
        pb[(j)&3][3] = *(const f16x8*)(pl + bo1);                                                  \
    }                                                                                              \
} while (0)

    // ---- chunk loop: 1 lgkm-only barrier per chunk; x staged mid-chunk into other buffer ----
#pragma unroll 1
    for (int c = 0; c < NCH; ++c) {
        f16* AHc = (c & 1) ? bufH1 : bufH0;
        f16* ALc = (c & 1) ? bufL1 : bufL0;
        f16* AHn = (c & 1) ? bufH0 : bufH1;
        f16* ALn = (c & 1) ? bufL0 : bufL1;
        const int more = (c < NCH - 1);
        const float* xq = xb + (c + 1) * KC;

        f32x4 xp0, xp1, xp2, xp3;
        if (more) {
            xp0 = *(const f32x4*)(xq);
            xp1 = *(const f32x4*)(xq + 64);
        }
        STEP(0);
        STEP(1);
        if (more) {
            cvt_write(AHn + wbase,      ALn + wbase,      xp0);
            cvt_write(AHn + wbase + 64, ALn + wbase + 64, xp1);
            xp2 = *(const f32x4*)(xq + 128);
            xp3 = *(const f32x4*)(xq + 192);
        }
        STEP(2);
        STEP(3);
        STEP(4);
        STEP(5);
        if (more) {
            cvt_write(AHn + wbase + 128, ALn + wbase + 128, xp2);
            cvt_write(AHn + wbase + 192, ALn + wbase + 192, xp3);
        }
        STEP(6);
        STEP(7);
        if (more) BAR();
    }
#undef STEP

    __syncthreads();   // protect LDS union before logits writes

    // ---- epilogue: descale + bias, write logits (C layout: col=lane&15, row=(lane>>4)*4+i) ----
#pragma unroll
    for (int m = 0; m < 2; m++) {
#pragma unroll
        for (int n = 0; n < 2; n++) {
            const int e = wv * 32 + n * 16 + eb;
            const float b = bias[e];
#pragma unroll
            for (int i = 0; i < 4; i++) {
                const int tk = m * 16 + kq * 4 + i;
                logits[tk][e] = (acc0[m][n][i] + acc1[m][n][i] * (1.0f / 2048.0f)) * (1.0f / 64.0f) + b;
            }
        }
    }
    __syncthreads();

    // ---- top-8 per token; each wave handles 4 tokens (verbatim inner loop) ----
    for (int tt = 0; tt < 4; tt++) {
        const int tok = wv * 4 + tt;
        float4 v4 = *(const float4*)&logits[tok][lane * 4];
        float lv[4] = {v4.x, v4.y, v4.z, v4.w};
        int msk = 0xF;
        float topv[TOPK];
        int   topi[TOPK];
#pragma unroll
        for (int r = 0; r < TOPK; r++) {
            float bvv = -INFINITY;
            int   bii = 0x7fffffff;
#pragma unroll
            for (int j = 0; j < 4; j++) {
                if (msk & (1 << j)) {
                    float vv = lv[j];
                    int   ii = lane * 4 + j;
                    if (vv > bvv || (vv == bvv && ii < bii)) { bvv = vv; bii = ii; }
                }
            }
#pragma unroll
            for (int off = 32; off > 0; off >>= 1) {
                float ov = __shfl_xor(bvv, off);
                int   oi = __shfl_xor(bii, off);
                if (ov > bvv || (ov == bvv && oi < bii)) { bvv = ov; bii = oi; }
            }
            topv[r] = bvv;
            topi[r] = bii;
            if ((bii >> 2) == lane) msk &= ~(1 << (bii & 3));
        }
        float m = topv[0];
        float s = 0.0f;
#pragma unroll
        for (int r = 0; r < TOPK; r++) s += expf(topv[r] - m);

        const int gtok = tok0 + tok;
        if (lane < TOPK) {
            out[(size_t)gtok * TOPK + lane] = expf(topv[lane] - m) / s;
        } else if (lane < 2 * TOPK) {
            int r = lane - TOPK;
            out[(size_t)TOKENS * TOPK + (size_t)gtok * TOPK + r] = (float)topi[r];
            atomicAdd(&hist[topi[r]], 1.0f);
        }
    }
    __syncthreads();
    if (tid < NEXP) {
        float hv = hist[tid];
        if (hv != 0.0f) atomicAdd(&out[(size_t)2 * TOKENS * TOPK + tid], hv);
    }

    // ---- fused stats: last block to finish computes them ----
    if (ctr) {
        __threadfence();
        if (tid == 0) {
            unsigned d = atomicAdd(ctr, 1u);
            lastflag = (d == gridDim.x - 1) ? 1u : 0u;
        }
        __syncthreads();
        if (lastflag) {
            float* counts = out + (size_t)2 * TOKENS * TOPK;
            float c = (tid < NEXP) ? *(volatile float*)&counts[tid] : 0.0f;
            float* sm = hist;
            if (tid < NEXP) sm[tid] = c;
            __syncthreads();
            for (int s = 128; s > 0; s >>= 1) {
                if (tid < s) sm[tid] += sm[tid + s];
                __syncthreads();
            }
            float mean = sm[0] / (float)NEXP;
            __syncthreads();
            if (tid < NEXP) { float d2 = c - mean; sm[tid] = d2 * d2; }
            __syncthreads();
            for (int s = 128; s > 0; s >>= 1) {
                if (tid < s) sm[tid] += sm[tid + s];
                __syncthreads();
            }
            float var = sm[0] / (float)(NEXP - 1);
            __syncthreads();
            if (tid < NEXP) sm[tid] = c;
            __syncthreads();
            for (int s = 128; s > 0; s >>= 1) {
                if (tid < s) sm[tid] = fmaxf(sm[tid], sm[tid + s]);
                __syncthreads();
            }
            float mx = sm[0];
            __syncthreads();
            if (tid < NEXP) sm[tid] = c;
            __syncthreads();
            for (int s = 128; s > 0; s >>= 1) {
                if (tid < s) sm[tid] = fminf(sm[tid], sm[tid + s]);
                __syncthreads();
            }
            float mn = sm[0];
            if (tid == 0) {
                float* scal = counts + NEXP;
                scal[0] = sqrtf(var) / (mean + 1e-6f);
                scal[1] = mx;
                scal[2] = mn;
                scal[3] = (float)(TOKENS * TOPK) / (float)NEXP;
            }
        }
    }
}

// ---------------- fallback (no workspace): fp32 VALU kernel ----------------
__global__ __launch_bounds__(256, 3) void k_main_fb(
        const float* __restrict__ x,
        const float* __restrict__ wsrc,
        const float* __restrict__ bias,
        float* __restrict__ out) {
    __shared__ float xT[16][BM];
    __shared__ float wS[16][NEXP];
    __shared__ float logits[BM][NEXP];
    __shared__ float hist[NEXP];

    const int tid  = threadIdx.x;
    const int tok0 = blockIdx.x * BM;
    const int ty   = tid >> 5;
    const int tx   = tid & 31;

    hist[tid] = 0.0f;

    float acc[4][8];
#pragma unroll
    for (int i = 0; i < 4; i++)
#pragma unroll
        for (int j = 0; j < 8; j++) acc[i][j] = 0.0f;

    const int lx_tok = tid >> 3;
    const int lx_d   = (tid & 7) * 2;

    for (int k0 = 0; k0 < DMODEL; k0 += 16) {
        __syncthreads();
        float2 xv = *(const float2*)&x[(size_t)(tok0 + lx_tok) * DMODEL + k0 + lx_d];
        xT[lx_d][lx_tok]     = xv.x;
        xT[lx_d + 1][lx_tok] = xv.y;
#pragma unroll
        for (int i = 0; i < 16; i++)
            wS[i][tid] = wsrc[(size_t)tid * DMODEL + k0 + i];
        __syncthreads();
#pragma unroll
        for (int k = 0; k < 16; k++) {
            float4 a  = *(const float4*)&xT[k][ty * 4];
            float4 b0 = *(const float4*)&wS[k][tx * 8];
            float4 b1 = *(const float4*)&wS[k][tx * 8 + 4];
            float av[4] = {a.x, a.y, a.z, a.w};
            float bv[8] = {b0.x, b0.y, b0.z, b0.w, b1.x, b1.y, b1.z, b1.w};
#pragma unroll
            for (int i = 0; i < 4; i++)
#pragma unroll
                for (int j = 0; j < 8; j++)
                    acc[i][j] = fmaf(av[i], bv[j], acc[i][j]);
        }
    }

    float bb[8];
#pragma unroll
    for (int j = 0; j < 8; j++) bb[j] = bias[tx * 8 + j];
#pragma unroll
    for (int i = 0; i < 4; i++) {
#pragma unroll
        for (int j = 0; j < 8; j++)
            logits[ty * 4 + i][tx * 8 + j] = acc[i][j] + bb[j];
    }
    __syncthreads();

    const int lane = tid & 63;
    const int wv   = tid >> 6;
    for (int tt = 0; tt < 8; tt++) {
        const int tok = wv * 8 + tt;
        float4 v4 = *(const float4*)&logits[tok][lane * 4];
        float lv[4] = {v4.x, v4.y, v4.z, v4.w};
        int msk = 0xF;
        float topv[TOPK];
        int   topi[TOPK];
#pragma unroll
        for (int r = 0; r < TOPK; r++) {
            float bvv = -INFINITY;
            int   bii = 0x7fffffff;
#pragma unroll
            for (int j = 0; j < 4; j++) {
                if (msk & (1 << j)) {
                    float vv = lv[j];
                    int   ii = lane * 4 + j;
                    if (vv > bvv || (vv == bvv && ii < bii)) { bvv = vv; bii = ii; }
                }
            }
#pragma unroll
            for (int off = 32; off > 0; off >>= 1) {
                float ov = __shfl_xor(bvv, off);
                int   oi = __shfl_xor(bii, off);
                if (ov > bvv || (ov == bvv && oi < bii)) { bvv = ov; bii = oi; }
            }
            topv[r] = bvv;
            topi[r] = bii;
            if ((bii >> 2) == lane) msk &= ~(1 << (bii & 3));
        }
        float m = topv[0];
        float s = 0.0f;
#pragma unroll
        for (int r = 0; r < TOPK; r++) s += expf(topv[r] - m);

        const int gtok = tok0 + tok;
        if (lane < TOPK) {
            out[(size_t)gtok * TOPK + lane] = expf(topv[lane] - m) / s;
        } else if (lane < 2 * TOPK) {
            int r = lane - TOPK;
            out[(size_t)TOKENS * TOPK + (size_t)gtok * TOPK + r] = (float)topi[r];
            atomicAdd(&hist[topi[r]], 1.0f);
        }
    }
    __syncthreads();
    float hv = hist[tid];
    if (hv != 0.0f) atomicAdd(&out[(size_t)2 * TOKENS * TOPK + tid], hv);
}

// ---------------- stats kernel (used when ws has no room for the done-counter) ----------------
__global__ void k_stats(float* __restrict__ out) {
    __shared__ float sm[NEXP];
    const float* counts = out + (size_t)2 * TOKENS * TOPK;
    const int t = threadIdx.x;
    float c = counts[t];

    sm[t] = c;
    __syncthreads();
    for (int s = 128; s > 0; s >>= 1) {
        if (t < s) sm[t] += sm[t + s];
        __syncthreads();
    }
    float mean = sm[0] / (float)NEXP;
    __syncthreads();

    float d = c - mean;
    sm[t] = d * d;
    __syncthreads();
    for (int s = 128; s > 0; s >>= 1) {
        if (t < s) sm[t] += sm[t + s];
        __syncthreads();
    }
    float var = sm[0] / (float)(NEXP - 1);
    __syncthreads();

    sm[t] = c;
    __syncthreads();
    for (int s = 128; s > 0; s >>= 1) {
        if (t < s) sm[t] = fmaxf(sm[t], sm[t + s]);
        __syncthreads();
    }
    float mx = sm[0];
    __syncthreads();

    sm[t] = c;
    __syncthreads();
    for (int s = 128; s > 0; s >>= 1) {
        if (t < s) sm[t] = fminf(sm[t], sm[t + s]);
        __syncthreads();
    }
    float mn = sm[0];

    if (t == 0) {
        float* scal = out + (size_t)2 * TOKENS * TOPK + NEXP;
        scal[0] = sqrtf(var) / (mean + 1e-6f);
        scal[1] = mx;
        scal[2] = mn;
        scal[3] = (float)(TOKENS * TOPK) / (float)NEXP;
    }
}

extern "C" void kernel_launch(void* const* d_in, const int* in_sizes, int n_in,
                              void* d_out, int out_size, void* d_ws, size_t ws_size,
                              hipStream_t stream) {
    const float* x    = (const float*)d_in[0];
    const float* w    = (const float*)d_in[1];
    const float* bias = (const float*)d_in[2];
    float* out = (float*)d_out;
    float* counts = out + (size_t)2 * TOKENS * TOPK;

    const size_t need = (size_t)DMODEL * NEXP * 2 * sizeof(_Float16);  // 2 MB
    if (ws_size >= need) {
        f16* wsH = (f16*)d_ws;
        f16* wsL = wsH + (size_t)DMODEL * NEXP;
        unsigned* ctr = (ws_size >= need + 64)
                            ? (unsigned*)((char*)d_ws + need) : (unsigned*)0;
        k_prep<<<(DMODEL * NEXP) / (256 * 8), 256, 0, stream>>>(w, wsH, wsL, counts, ctr);
        k_main<<<TOKENS / BM, 512, 0, stream>>>(x, wsH, wsL, bias, out, ctr);
        if (!ctr) k_stats<<<1, NEXP, 0, stream>>>(out);
    } else {
        k_zero<<<1, NEXP, 0, stream>>>(counts);
        k_main_fb<<<TOKENS / BM, 256, 0, stream>>>(x, w, bias, out);
        k_stats<<<1, NEXP, 0, stream>>>(out);
    }
}

// Round 8
// 305.554 us; speedup vs baseline: 1.2693x; 1.2693x over previous
//
#include <hip/hip_runtime.h>
#include <math.h>

#define TOKENS 16384
#define DMODEL 2048
#define NEXP   256
#define TOPK   8
#define BM     64               // tokens per block
#define FBM    32               // fallback kernel tile
#define KC     256              // k-chunk (floats) staged in LDS per barrier pair
#define NCH    (DMODEL / KC)    // 8 chunks
#define NTIL   (DMODEL / 32)    // 64 flat k-tiles
#define RS     264              // LDS row stride in halfs (256 + 8 pad)

typedef _Float16 f16;
typedef _Float16 f16x8 __attribute__((ext_vector_type(8)));
typedef _Float16 f16x4 __attribute__((ext_vector_type(4)));
typedef float    f32x4 __attribute__((ext_vector_type(4)));

// barrier that drains ONLY lgkm (LDS); global prefetch stays in flight
#define BAR() asm volatile("s_waitcnt lgkmcnt(0)\ns_barrier" ::: "memory")

// f32x4 -> split-f16 (hi, lo*2048) -> LDS
static __device__ __forceinline__ void cvt_write(f16* AHp, f16* ALp, f32x4 v) {
    f16 h0 = (f16)v.x, h1 = (f16)v.y, h2 = (f16)v.z, h3 = (f16)v.w;
    f16x4 hv = {h0, h1, h2, h3};
    f16x4 lv = {(f16)((v.x - (float)h0) * 2048.0f),
                (f16)((v.y - (float)h1) * 2048.0f),
                (f16)((v.z - (float)h2) * 2048.0f),
                (f16)((v.w - (float)h3) * 2048.0f)};
    *(f16x4*)AHp = hv;
    *(f16x4*)ALp = lv;
}

// ---------------- prep: w (E x D f32) -> fp16 split planes, tile-major; zero counts/ctr ----------------
// plane layout: idx = t*(NEXP*32) + e*32 + ki   (t = d>>5, ki = d&31); 8 elems/thread
__global__ void k_prep(const float* __restrict__ w,
                       f16* __restrict__ wsH, f16* __restrict__ wsL,
                       float* __restrict__ counts, unsigned* __restrict__ ctr) {
    const int tid = threadIdx.x;
    if (blockIdx.x == 0) {
        counts[tid] = 0.0f;
        if (tid == 0 && ctr) *ctr = 0u;
    }
    const int g8 = (blockIdx.x * 256 + tid) * 8;
    const int ki = g8 & 31;
    const int e  = (g8 >> 5) & 255;
    const int t  = g8 >> 13;
    const float* src = w + (size_t)e * DMODEL + t * 32 + ki;
    f16x8 hv, lv;
#pragma unroll
    for (int i = 0; i < 8; i++) {
        float v = src[i] * 64.0f;
        f16 h = (f16)v;
        hv[i] = h;
        lv[i] = (f16)((v - (float)h) * 2048.0f);
    }
    *(f16x8*)(wsH + g8) = hv;
    *(f16x8*)(wsL + g8) = lv;
}

__global__ void k_zero(float* __restrict__ counts) {
    counts[threadIdx.x] = 0.0f;
}

// ---------------- main: BM=64, 8-wave, depth-4 B pipeline, split-fp16 MFMA + top-8 + stats ----------------
__global__ __launch_bounds__(512, 2) void k_main(
        const float* __restrict__ x,
        const f16*   __restrict__ wh,
        const f16*   __restrict__ wl,
        const float* __restrict__ bias,
        float* __restrict__ out,
        unsigned* __restrict__ ctr) {
    // A (hi+lo planes, single buffer); logits overlays the same LDS after the GEMM
    __shared__ __align__(16) char raw[2 * BM * RS * sizeof(f16)];   // 67584 B >= 65536 (logits 64x256)
    __shared__ float hist[NEXP];
    __shared__ unsigned lastflag;

    f16* AH = (f16*)raw;
    f16* AL = AH + BM * RS;
    float (*logits)[NEXP] = (float (*)[NEXP])raw;

    const int tid  = threadIdx.x;
    const int tok0 = blockIdx.x * BM;
    const int lane = tid & 63;
    const int wv   = tid >> 6;            // 0..7, owns experts wv*32..wv*32+31
    const int eb   = lane & 15;
    const int kq   = lane >> 4;           // 0..3

    if (tid < NEXP) hist[tid] = 0.0f;

    // ---- x staging: thread -> token (tid>>3), 8 x f32x4 at (tid&7)*4 + s*32 ----
    const int s_tok  = tid >> 3;          // 0..63
    const int s_lane = tid & 7;           // 0..7
    const float* xb = x + (size_t)(tok0 + s_tok) * DMODEL + s_lane * 4;
    const int wbase = s_tok * RS + s_lane * 4;      // halfs

    // ---- A fragment read offsets (halfs): 4 m-frags ----
    const int ro0 = (eb) * RS + kq * 8;
    const int ro1 = (16 + eb) * RS + kq * 8;
    const int ro2 = (32 + eb) * RS + kq * 8;
    const int ro3 = (48 + eb) * RS + kq * 8;

    // ---- B fragment offsets within a k-tile (halfs): wave owns 2 n-frags ----
    const int bo0 = (wv * 32 + eb) * 32 + kq * 8;
    const int bo1 = (wv * 32 + 16 + eb) * 32 + kq * 8;

    f32x4 acc0[4][2], acc1[4][2];
#pragma unroll
    for (int m = 0; m < 4; m++)
#pragma unroll
        for (int n = 0; n < 2; n++) {
            acc0[m][n] = (f32x4){0.0f, 0.0f, 0.0f, 0.0f};
            acc1[m][n] = (f32x4){0.0f, 0.0f, 0.0f, 0.0f};
        }

    // ---- prologue: stage x chunk 0; prime 4-deep B pipeline (tiles 0..3) ----
    {
        f32x4 xv[8];
#pragma unroll
        for (int s = 0; s < 8; s++) xv[s] = *(const f32x4*)(xb + s * 32);
#pragma unroll
        for (int s = 0; s < 8; s++)
            cvt_write(AH + wbase + s * 32, AL + wbase + s * 32, xv[s]);
    }
    f16x8 pb[4][4];                       // [slot][bh0,bh1,bl0,bl1] — static indices only
#pragma unroll
    for (int s = 0; s < 4; ++s) {
        const f16* ph = wh + (size_t)s * (NEXP * 32);
        const f16* pl = wl + (size_t)s * (NEXP * 32);
        pb[s][0] = *(const f16x8*)(ph + bo0);
        pb[s][1] = *(const f16x8*)(ph + bo1);
        pb[s][2] = *(const f16x8*)(pl + bo0);
        pb[s][3] = *(const f16x8*)(pl + bo1);
    }
    BAR();

// one k-tile: 8 ds_read A frags, 24 MFMA, then refill this slot with tile t+4
// (refill AFTER consumption; 3-tile in-flight window ≈ 700 cyc covers L2/L3 latency)
#define STEP(j) do {                                                                               \
    const int co = (j) * 32;                                                                       \
    f16x8 a0h = *(const f16x8*)(AH + ro0 + co);                                                    \
    f16x8 a1h = *(const f16x8*)(AH + ro1 + co);                                                    \
    f16x8 a2h = *(const f16x8*)(AH + ro2 + co);                                                    \
    f16x8 a3h = *(const f16x8*)(AH + ro3 + co);                                                    \
    f16x8 a0l = *(const f16x8*)(AL + ro0 + co);                                                    \
    f16x8 a1l = *(const f16x8*)(AL + ro1 + co);                                                    \
    f16x8 a2l = *(const f16x8*)(AL + ro2 + co);                                                    \
    f16x8 a3l = *(const f16x8*)(AL + ro3 + co);                                                    \
    __builtin_amdgcn_s_setprio(1);                                                                 \
    acc0[0][0] = __builtin_amdgcn_mfma_f32_16x16x32_f16(a0h, pb[(j)&3][0], acc0[0][0], 0, 0, 0);   \
    acc0[0][1] = __builtin_amdgcn_mfma_f32_16x16x32_f16(a0h, pb[(j)&3][1], acc0[0][1], 0, 0, 0);   \
    acc0[1][0] = __builtin_amdgcn_mfma_f32_16x16x32_f16(a1h, pb[(j)&3][0], acc0[1][0], 0, 0, 0);   \
    acc0[1][1] = __builtin_amdgcn_mfma_f32_16x16x32_f16(a1h, pb[(j)&3][1], acc0[1][1], 0, 0, 0);   \
    acc0[2][0] = __builtin_amdgcn_mfma_f32_16x16x32_f16(a2h, pb[(j)&3][0], acc0[2][0], 0, 0, 0);   \
    acc0[2][1] = __builtin_amdgcn_mfma_f32_16x16x32_f16(a2h, pb[(j)&3][1], acc0[2][1], 0, 0, 0);   \
    acc0[3][0] = __builtin_amdgcn_mfma_f32_16x16x32_f16(a3h, pb[(j)&3][0], acc0[3][0], 0, 0, 0);   \
    acc0[3][1] = __builtin_amdgcn_mfma_f32_16x16x32_f16(a3h, pb[(j)&3][1], acc0[3][1], 0, 0, 0);   \
    acc1[0][0] = __builtin_amdgcn_mfma_f32_16x16x32_f16(a0l, pb[(j)&3][0], acc1[0][0], 0, 0, 0);   \
    acc1[0][1] = __builtin_amdgcn_mfma_f32_16x16x32_f16(a0l, pb[(j)&3][1], acc1[0][1], 0, 0, 0);   \
    acc1[1][0] = __builtin_amdgcn_mfma_f32_16x16x32_f16(a1l, pb[(j)&3][0], acc1[1][0], 0, 0, 0);   \
    acc1[1][1] = __builtin_amdgcn_mfma_f32_16x16x32_f16(a1l, pb[(j)&3][1], acc1[1][1], 0, 0, 0);   \
    acc1[2][0] = __builtin_amdgcn_mfma_f32_16x16x32_f16(a2l, pb[(j)&3][0], acc1[2][0], 0, 0, 0);   \
    acc1[2][1] = __builtin_amdgcn_mfma_f32_16x16x32_f16(a2l, pb[(j)&3][1], acc1[2][1], 0, 0, 0);   \
    acc1[3][0] = __builtin_amdgcn_mfma_f32_16x16x32_f16(a3l, pb[(j)&3][0], acc1[3][0], 0, 0, 0);   \
    acc1[3][1] = __builtin_amdgcn_mfma_f32_16x16x32_f16(a3l, pb[(j)&3][1], acc1[3][1], 0, 0, 0);   \
    acc1[0][0] = __builtin_amdgcn_mfma_f32_16x16x32_f16(a0h, pb[(j)&3][2], acc1[0][0], 0, 0, 0);   \
    acc1[0][1] = __builtin_amdgcn_mfma_f32_16x16x32_f16(a0h, pb[(j)&3][3], acc1[0][1], 0, 0, 0);   \
    acc1[1][0] = __builtin_amdgcn_mfma_f32_16x16x32_f16(a1h, pb[(j)&3][2], acc1[1][0], 0, 0, 0);   \
    acc1[1][1] = __builtin_amdgcn_mfma_f32_16x16x32_f16(a1h, pb[(j)&3][3], acc1[1][1], 0, 0, 0);   \
    acc1[2][0] = __builtin_amdgcn_mfma_f32_16x16x32_f16(a2h, pb[(j)&3][2], acc1[2][0], 0, 0, 0);   \
    acc1[2][1] = __builtin_amdgcn_mfma_f32_16x16x32_f16(a2h, pb[(j)&3][3], acc1[2][1], 0, 0, 0);   \
    acc1[3][0] = __builtin_amdgcn_mfma_f32_16x16x32_f16(a3h, pb[(j)&3][2], acc1[3][0], 0, 0, 0);   \
    acc1[3][1] = __builtin_amdgcn_mfma_f32_16x16x32_f16(a3h, pb[(j)&3][3], acc1[3][1], 0, 0, 0);   \
    __builtin_amdgcn_s_setprio(0);                                                                 \
    if ((c < NCH - 1) || ((j) < 4)) {                                                              \
        const int t4 = c * 8 + (j) + 4;                                                            \
        const f16* ph = wh + (size_t)t4 * (NEXP * 32);                                             \
        const f16* pl = wl + (size_t)t4 * (NEXP * 32);                                             \
        pb[(j)&3][0] = *(const f16x8*)(ph + bo0);                                                  \
        pb[(j)&3][1] = *(const f16x8*)(ph + bo1);                                                  \
        pb[(j)&3][2] = *(const f16x8*)(pl + bo0);                                                  \
        pb[(j)&3][3] = *(const f16x8*)(pl + bo1);                                                  \
    }                                                                                              \
} while (0)

    // ---- chunk loop: x(c+1) regs loaded at top (in flight across whole chunk); 2 lgkm barriers ----
#pragma unroll 1
    for (int c = 0; c < NCH; ++c) {
        const int more = (c < NCH - 1);
        f32x4 xr[8];
        if (more) {
            const float* xq = xb + (c + 1) * KC;
#pragma unroll
            for (int s = 0; s < 8; s++) xr[s] = *(const f32x4*)(xq + s * 32);
        }
        STEP(0);
        STEP(1);
        STEP(2);
        STEP(3);
        STEP(4);
        STEP(5);
        STEP(6);
        STEP(7);
        if (more) {
            BAR();   // all waves done reading chunk c
#pragma unroll
            for (int s = 0; s < 8; s++)
                cvt_write(AH + wbase + s * 32, AL + wbase + s * 32, xr[s]);
            BAR();   // chunk c+1 visible
        }
    }
#undef STEP

    __syncthreads();   // protect LDS union before logits writes

    // ---- epilogue: descale + bias, write logits (C layout: col=lane&15, row=(lane>>4)*4+i) ----
#pragma unroll
    for (int m = 0; m < 4; m++) {
#pragma unroll
        for (int n = 0; n < 2; n++) {
            const int e = wv * 32 + n * 16 + eb;
            const float b = bias[e];
#pragma unroll
            for (int i = 0; i < 4; i++) {
                const int tk = m * 16 + kq * 4 + i;
                logits[tk][e] = (acc0[m][n][i] + acc1[m][n][i] * (1.0f / 2048.0f)) * (1.0f / 64.0f) + b;
            }
        }
    }
    __syncthreads();

    // ---- top-8 per token; each wave handles 8 tokens (verbatim from passing kernel) ----
    for (int tt = 0; tt < 8; tt++) {
        const int tok = wv * 8 + tt;
        float4 v4 = *(const float4*)&logits[tok][lane * 4];
        float lv[4] = {v4.x, v4.y, v4.z, v4.w};
        int msk = 0xF;
        float topv[TOPK];
        int   topi[TOPK];
#pragma unroll
        for (int r = 0; r < TOPK; r++) {
            float bvv = -INFINITY;
            int   bii = 0x7fffffff;
#pragma unroll
            for (int j = 0; j < 4; j++) {
                if (msk & (1 << j)) {
                    float vv = lv[j];
                    int   ii = lane * 4 + j;
                    if (vv > bvv || (vv == bvv && ii < bii)) { bvv = vv; bii = ii; }
                }
            }
#pragma unroll
            for (int off = 32; off > 0; off >>= 1) {
                float ov = __shfl_xor(bvv, off);
                int   oi = __shfl_xor(bii, off);
                if (ov > bvv || (ov == bvv && oi < bii)) { bvv = ov; bii = oi; }
            }
            topv[r] = bvv;
            topi[r] = bii;
            if ((bii >> 2) == lane) msk &= ~(1 << (bii & 3));
        }
        float m = topv[0];
        float s = 0.0f;
#pragma unroll
        for (int r = 0; r < TOPK; r++) s += expf(topv[r] - m);

        const int gtok = tok0 + tok;
        if (lane < TOPK) {
            out[(size_t)gtok * TOPK + lane] = expf(topv[lane] - m) / s;
        } else if (lane < 2 * TOPK) {
            int r = lane - TOPK;
            out[(size_t)TOKENS * TOPK + (size_t)gtok * TOPK + r] = (float)topi[r];
            atomicAdd(&hist[topi[r]], 1.0f);
        }
    }
    __syncthreads();
    if (tid < NEXP) {
        float hv = hist[tid];
        if (hv != 0.0f) atomicAdd(&out[(size_t)2 * TOKENS * TOPK + tid], hv);
    }

    // ---- fused stats: last block to finish computes them ----
    if (ctr) {
        __threadfence();
        if (tid == 0) {
            unsigned d = atomicAdd(ctr, 1u);
            lastflag = (d == gridDim.x - 1) ? 1u : 0u;
        }
        __syncthreads();
        if (lastflag) {
            float* counts = out + (size_t)2 * TOKENS * TOPK;
            float c = (tid < NEXP) ? *(volatile float*)&counts[tid] : 0.0f;
            float* sm = hist;
            if (tid < NEXP) sm[tid] = c;
            __syncthreads();
            for (int s = 128; s > 0; s >>= 1) {
                if (tid < s) sm[tid] += sm[tid + s];
                __syncthreads();
            }
            float mean = sm[0] / (float)NEXP;
            __syncthreads();
            if (tid < NEXP) { float d2 = c - mean; sm[tid] = d2 * d2; }
            __syncthreads();
            for (int s = 128; s > 0; s >>= 1) {
                if (tid < s) sm[tid] += sm[tid + s];
                __syncthreads();
            }
            float var = sm[0] / (float)(NEXP - 1);
            __syncthreads();
            if (tid < NEXP) sm[tid] = c;
            __syncthreads();
            for (int s = 128; s > 0; s >>= 1) {
                if (tid < s) sm[tid] = fmaxf(sm[tid], sm[tid + s]);
                __syncthreads();
            }
            float mx = sm[0];
            __syncthreads();
            if (tid < NEXP) sm[tid] = c;
            __syncthreads();
            for (int s = 128; s > 0; s >>= 1) {
                if (tid < s) sm[tid] = fminf(sm[tid], sm[tid + s]);
                __syncthreads();
            }
            float mn = sm[0];
            if (tid == 0) {
                float* scal = counts + NEXP;
                scal[0] = sqrtf(var) / (mean + 1e-6f);
                scal[1] = mx;
                scal[2] = mn;
                scal[3] = (float)(TOKENS * TOPK) / (float)NEXP;
            }
        }
    }
}

// ---------------- fallback (no workspace): fp32 VALU kernel (32-token tile) ----------------
__global__ __launch_bounds__(256, 3) void k_main_fb(
        const float* __restrict__ x,
        const float* __restrict__ wsrc,
        const float* __restrict__ bias,
        float* __restrict__ out) {
    __shared__ float xT[16][FBM];
    __shared__ float wS[16][NEXP];
    __shared__ float logits[FBM][NEXP];
    __shared__ float hist[NEXP];

    const int tid  = threadIdx.x;
    const int tok0 = blockIdx.x * FBM;
    const int ty   = tid >> 5;
    const int tx   = tid & 31;

    hist[tid] = 0.0f;

    float acc[4][8];
#pragma unroll
    for (int i = 0; i < 4; i++)
#pragma unroll
        for (int j = 0; j < 8; j++) acc[i][j] = 0.0f;

    const int lx_tok = tid >> 3;
    const int lx_d   = (tid & 7) * 2;

    for (int k0 = 0; k0 < DMODEL; k0 += 16) {
        __syncthreads();
        float2 xv = *(const float2*)&x[(size_t)(tok0 + lx_tok) * DMODEL + k0 + lx_d];
        xT[lx_d][lx_tok]     = xv.x;
        xT[lx_d + 1][lx_tok] = xv.y;
#pragma unroll
        for (int i = 0; i < 16; i++)
            wS[i][tid] = wsrc[(size_t)tid * DMODEL + k0 + i];
        __syncthreads();
#pragma unroll
        for (int k = 0; k < 16; k++) {
            float4 a  = *(const float4*)&xT[k][ty * 4];
            float4 b0 = *(const float4*)&wS[k][tx * 8];
            float4 b1 = *(const float4*)&wS[k][tx * 8 + 4];
            float av[4] = {a.x, a.y, a.z, a.w};
            float bv[8] = {b0.x, b0.y, b0.z, b0.w, b1.x, b1.y, b1.z, b1.w};
#pragma unroll
            for (int i = 0; i < 4; i++)
#pragma unroll
                for (int j = 0; j < 8; j++)
                    acc[i][j] = fmaf(av[i], bv[j], acc[i][j]);
        }
    }

    float bb[8];
#pragma unroll
    for (int j = 0; j < 8; j++) bb[j] = bias[tx * 8 + j];
#pragma unroll
    for (int i = 0; i < 4; i++) {
#pragma unroll
        for (int j = 0; j < 8; j++)
            logits[ty * 4 + i][tx * 8 + j] = acc[i][j] + bb[j];
    }
    __syncthreads();

    const int lane = tid & 63;
    const int wv   = tid >> 6;
    for (int tt = 0; tt < 8; tt++) {
        const int tok = wv * 8 + tt;
        float4 v4 = *(const float4*)&logits[tok][lane * 4];
        float lv[4] = {v4.x, v4.y, v4.z, v4.w};
        int msk = 0xF;
        float topv[TOPK];
        int   topi[TOPK];
#pragma unroll
        for (int r = 0; r < TOPK; r++) {
            float bvv = -INFINITY;
            int   bii = 0x7fffffff;
#pragma unroll
            for (int j = 0; j < 4; j++) {
                if (msk & (1 << j)) {
                    float vv = lv[j];
                    int   ii = lane * 4 + j;
                    if (vv > bvv || (vv == bvv && ii < bii)) { bvv = vv; bii = ii; }
                }
            }
#pragma unroll
            for (int off = 32; off > 0; off >>= 1) {
                float ov = __shfl_xor(bvv, off);
                int   oi = __shfl_xor(bii, off);
                if (ov > bvv || (ov == bvv && oi < bii)) { bvv = ov; bii = oi; }
            }
            topv[r] = bvv;
            topi[r] = bii;
            if ((bii >> 2) == lane) msk &= ~(1 << (bii & 3));
        }
        float m = topv[0];
        float s = 0.0f;
#pragma unroll
        for (int r = 0; r < TOPK; r++) s += expf(topv[r] - m);

        const int gtok = tok0 + tok;
        if (lane < TOPK) {
            out[(size_t)gtok * TOPK + lane] = expf(topv[lane] - m) / s;
        } else if (lane < 2 * TOPK) {
            int r = lane - TOPK;
            out[(size_t)TOKENS * TOPK + (size_t)gtok * TOPK + r] = (float)topi[r];
            atomicAdd(&hist[topi[r]], 1.0f);
        }
    }
    __syncthreads();
    float hv = hist[tid];
    if (hv != 0.0f) atomicAdd(&out[(size_t)2 * TOKENS * TOPK + tid], hv);
}

// ---------------- stats kernel (used when ws has no room for the done-counter) ----------------
__global__ void k_stats(float* __restrict__ out) {
    __shared__ float sm[NEXP];
    const float* counts = out + (size_t)2 * TOKENS * TOPK;
    const int t = threadIdx.x;
    float c = counts[t];

    sm[t] = c;
    __syncthreads();
    for (int s = 128; s > 0; s >>= 1) {
        if (t < s) sm[t] += sm[t + s];
        __syncthreads();
    }
    float mean = sm[0] / (float)NEXP;
    __syncthreads();

    float d = c - mean;
    sm[t] = d * d;
    __syncthreads();
    for (int s = 128; s > 0; s >>= 1) {
        if (t < s) sm[t] += sm[t + s];
        __syncthreads();
    }
    float var = sm[0] / (float)(NEXP - 1);
    __syncthreads();

    sm[t] = c;
    __syncthreads();
    for (int s = 128; s > 0; s >>= 1) {
        if (t < s) sm[t] = fmaxf(sm[t], sm[t + s]);
        __syncthreads();
    }
    float mx = sm[0];
    __syncthreads();

    sm[t] = c;
    __syncthreads();
    for (int s = 128; s > 0; s >>= 1) {
        if (t < s) sm[t] = fminf(sm[t], sm[t + s]);
        __syncthreads();
    }
    float mn = sm[0];

    if (t == 0) {
        float* scal = out + (size_t)2 * TOKENS * TOPK + NEXP;
        scal[0] = sqrtf(var) / (mean + 1e-6f);
        scal[1] = mx;
        scal[2] = mn;
        scal[3] = (float)(TOKENS * TOPK) / (float)NEXP;
    }
}

extern "C" void kernel_launch(void* const* d_in, const int* in_sizes, int n_in,
                              void* d_out, int out_size, void* d_ws, size_t ws_size,
                              hipStream_t stream) {
    const float* x    = (const float*)d_in[0];
    const float* w    = (const float*)d_in[1];
    const float* bias = (const float*)d_in[2];
    float* out = (float*)d_out;
    float* counts = out + (size_t)2 * TOKENS * TOPK;

    const size_t need = (size_t)DMODEL * NEXP * 2 * sizeof(_Float16);  // 2 MB
    if (ws_size >= need) {
        f16* wsH = (f16*)d_ws;
        f16* wsL = wsH + (size_t)DMODEL * NEXP;
        unsigned* ctr = (ws_size >= need + 64)
                            ? (unsigned*)((char*)d_ws + need) : (unsigned*)0;
        k_prep<<<(DMODEL * NEXP) / (256 * 8), 256, 0, stream>>>(w, wsH, wsL, counts, ctr);
        k_main<<<TOKENS / BM, 512, 0, stream>>>(x, wsH, wsL, bias, out, ctr);
        if (!ctr) k_stats<<<1, NEXP, 0, stream>>>(out);
    } else {
        k_zero<<<1, NEXP, 0, stream>>>(counts);
        k_main_fb<<<TOKENS / FBM, 256, 0, stream>>>(x, w, bias, out);
        k_stats<<<1, NEXP, 0, stream>>>(out);
    }
}